// Round 4
// baseline (1626.775 us; speedup 1.0000x reference)
//
#include <hip/hip_runtime.h>

// VQ-VAE VectorQuantizer forward + EMA update, MI355X (gfx950).
// Distance argmin bit-exactly emulates the numpy fp32 reference:
//   dist = pairwise_sum(x*x) - 2*(sgemm single-FMA-chain) + pairwise_sum(w*w)
// R3: codebook operand moved to the SCALAR pipe (s_load of wT rows, FMA with
// SGPR src); z tile LDS-resident once per block; zero K-loop barriers.

#define NTOK 16384
#define KC   8192
#define DD   256

#define OFF_Q    0
#define OFF_LOSS 4194304
#define OFF_IDX  4194305
#define OFF_W    4210689
#define OFF_CS   6307841
#define OFF_EMA  6316033

#define DECAY_F  0.99f
#define OMD_F    0.01f
#define EPS_F    1e-5f
#define KEPS_F   0.08192f   // K * eps

// ---- numpy-pairwise row squared-norm body (n=256): two 128 halves, 8
// strided accumulators each, butterfly combine — bit-exact vs numpy.
__device__ __forceinline__ void rownorm_body(const float* __restrict__ a,
                                             float* __restrict__ outn, int rb) {
    const int wave = threadIdx.x >> 6, lane = threadIdx.x & 63;
    const int row  = rb * 16 + wave * 4 + (lane >> 4);
    const int p    = lane & 15;
    const int h    = p >> 3, j = p & 7;
    const float* base = a + row * DD + h * 128 + j;
    float v = base[0];
    float r = __fmul_rn(v, v);
    #pragma unroll
    for (int t = 1; t < 16; ++t) {
        v = base[8 * t];
        r = __fadd_rn(r, __fmul_rn(v, v));
    }
    r = __fadd_rn(r, __shfl_xor(r, 1));
    r = __fadd_rn(r, __shfl_xor(r, 2));
    r = __fadd_rn(r, __shfl_xor(r, 4));
    r = __fadd_rn(r, __shfl_xor(r, 8));
    if (p == 0) outn[row] = r;
}

// ---------------- fused prep: wT transpose + row norms + EMA init ----------
__global__ __launch_bounds__(256) void k_prep(const float* __restrict__ z,
                                              const float* __restrict__ w,
                                              const float* __restrict__ ecs,
                                              const float* __restrict__ emaw,
                                              float* __restrict__ out,
                                              float* __restrict__ x2v,
                                              float* __restrict__ w2v,
                                              float* __restrict__ lossacc) {
    const int b = blockIdx.x;
    if (b < 2048) {                         // w[8192][256] -> wT[256][8192]
        __shared__ float s[32][33];
        const int tx = threadIdx.x & 31, ty = threadIdx.x >> 5;
        const int c0 = (b & 7) * 32, r0 = (b >> 3) * 32;
        #pragma unroll
        for (int i = 0; i < 4; ++i)
            s[ty + i * 8][tx] = w[(size_t)(r0 + ty + i * 8) * DD + c0 + tx];
        __syncthreads();
        #pragma unroll
        for (int i = 0; i < 4; ++i)
            out[OFF_W + (size_t)(c0 + ty + i * 8) * KC + r0 + tx] = s[tx][ty + i * 8];
    } else if (b < 3072) {
        rownorm_body(z, x2v, b - 2048);     // 1024 blocks: NTOK/16
    } else if (b < 3584) {
        rownorm_body(w, w2v, b - 3072);     // 512 blocks: KC/16
    } else {                                // EMA init, 8192 blocks
        const int i = (b - 3584) * 256 + threadIdx.x;
        out[OFF_EMA + i] = __fmul_rn(DECAY_F, emaw[i]);
        if (i < KC) out[OFF_CS + i] = __fmul_rn(DECAY_F, ecs[i]);
        if (i == 0) *lossacc = 0.0f;
    }
}

// ---------------- argmin: z in LDS (once), w via scalar pipe ---------------
// grid 1024 = 256 row-blocks x 4 code-splits. Block: 64 rows (lane=row),
// wave wv covers codes {split*2048 + pass*128 + wv*32 ..+31}, 16 passes.
// acc[c] = single fp32 FMA chain over d=0..255 ascending (BLAS-exact).
__global__ __launch_bounds__(256, 2) void k_argmin(
        const float* __restrict__ z, const float* __restrict__ wT,
        const float* __restrict__ x2v, const float* __restrict__ w2v,
        float* __restrict__ vbuf, int* __restrict__ kbuf) {
    __shared__ float Zs[DD * 64];           // [d][row], 64 KB

    const int tid   = threadIdx.x;
    const int l     = tid & 63;             // row within block
    const int q     = tid >> 6;             // d-quarter for staging
    const int wv    = __builtin_amdgcn_readfirstlane(q);   // uniform wave id
    const int split = blockIdx.x & 3;       // pairs of XCDs share a w-split
    const int rb    = blockIdx.x >> 2;
    const int n0    = rb * 64;
    const int cbase = split * 2048;

    // stage z[n0..n0+63][0..255] transposed into LDS (once per block)
    #pragma unroll
    for (int f = 0; f < 16; ++f) {
        const float4 v = *(const float4*)&z[(size_t)(n0 + l) * DD + q * 64 + f * 4];
        Zs[(q * 64 + f * 4 + 0) * 64 + l] = v.x;
        Zs[(q * 64 + f * 4 + 1) * 64 + l] = v.y;
        Zs[(q * 64 + f * 4 + 2) * 64 + l] = v.z;
        Zs[(q * 64 + f * 4 + 3) * 64 + l] = v.w;
    }
    __syncthreads();

    const float x2r = x2v[n0 + l];
    float bestv = 1e30f;
    int   bestk = 0;

    for (int pass = 0; pass < 16; ++pass) {
        const int c0 = cbase + pass * 128 + wv * 32;   // uniform
        float acc[32];
        #pragma unroll
        for (int c = 0; c < 32; ++c) acc[c] = 0.0f;

        #pragma unroll 2
        for (int d = 0; d < DD; ++d) {
            const float zv = Zs[d * 64 + l];                       // per-lane
            const float* __restrict__ wr = wT + (size_t)d * KC + c0; // uniform -> s_load
            #pragma unroll
            for (int c = 0; c < 32; ++c)
                acc[c] = __fmaf_rn(wr[c], zv, acc[c]);
        }

        // dist = (x2 - 2*xe) + w2, per-op fp32 rounding; codes ascend over
        // (pass, c) -> strict '<' keeps first occurrence (np.argmin rule).
        #pragma unroll
        for (int c = 0; c < 32; ++c) {
            const int   code = c0 + c;
            const float dv   = __fadd_rn(
                __fsub_rn(x2r, __fmul_rn(2.0f, acc[c])), w2v[code]);
            if (dv < bestv) { bestv = dv; bestk = code; }
        }
    }

    const int slot = split * 4 + wv;        // 16 candidate slots per row
    vbuf[slot * NTOK + n0 + l] = bestv;
    kbuf[slot * NTOK + n0 + l] = bestk;
}

// ---------------- combine the 16 candidates per row ------------------------
__global__ __launch_bounds__(256) void k_reduce(const float* __restrict__ vbuf,
                                                const int* __restrict__ kbuf,
                                                int* __restrict__ idx_ws,
                                                float* __restrict__ out) {
    const int r = blockIdx.x * 256 + threadIdx.x;
    float bv = vbuf[r];
    int   bk = kbuf[r];
    #pragma unroll
    for (int s = 1; s < 16; ++s) {
        const float v = vbuf[s * NTOK + r];
        const int   k = kbuf[s * NTOK + r];
        if (v < bv || (v == bv && k < bk)) { bv = v; bk = k; }
    }
    idx_ws[r] = bk;
    out[OFF_IDX + r] = (float)bk;
}

// ---------------- gather quantized + loss partial + EMA scatter ------------
__global__ __launch_bounds__(256) void k_scatter(const float* __restrict__ z,
                                                 const float* __restrict__ w,
                                                 const int* __restrict__ idx_ws,
                                                 float* __restrict__ out,
                                                 float* __restrict__ lossacc) {
    const int n = blockIdx.x, d = threadIdx.x;
    const int k = idx_ws[n];
    const float zv   = z[n * DD + d];
    const float q    = w[k * DD + d];
    const float diff = __fsub_rn(q, zv);
    out[OFF_Q + n * DD + d] = __fadd_rn(zv, diff);   // straight-through value

    float s = __fmul_rn(diff, diff);
    #pragma unroll
    for (int off = 32; off; off >>= 1) s += __shfl_down(s, off, 64);
    __shared__ float ps[4];
    if ((d & 63) == 0) ps[d >> 6] = s;
    __syncthreads();
    if (d == 0) atomicAdd(lossacc, ps[0] + ps[1] + ps[2] + ps[3]);

    atomicAdd(&out[OFF_EMA + k * DD + d], __fmul_rn(OMD_F, zv));
    if (d == 0) atomicAdd(&out[OFF_CS + k], OMD_F);
}

// ---------------- n = sum(new_cluster_size); finalize loss -----------------
__global__ __launch_bounds__(256) void k_nsum(float* __restrict__ out,
                                              const float* __restrict__ lossacc,
                                              float* __restrict__ nsum) {
    const int t = threadIdx.x;
    float s = 0.0f;
    for (int i = t; i < KC; i += 256) s += out[OFF_CS + i];
    #pragma unroll
    for (int off = 32; off; off >>= 1) s += __shfl_down(s, off, 64);
    __shared__ float ps[4];
    if ((t & 63) == 0) ps[t >> 6] = s;
    __syncthreads();
    if (t == 0) {
        *nsum = ps[0] + ps[1] + ps[2] + ps[3];
        out[OFF_LOSS] = 1.25f * (*lossacc) / 4194304.0f;
    }
}

// ---------------- new_weight = new_ema_w / laplace(cluster_size) -----------
__global__ __launch_bounds__(256) void k_neww(float* __restrict__ out,
                                              const float* __restrict__ nsum) {
    const int k = blockIdx.x, d = threadIdx.x;
    const float n  = *nsum;
    const float cs = __fmul_rn(__fdiv_rn(__fadd_rn(out[OFF_CS + k], EPS_F),
                                         __fadd_rn(n, KEPS_F)), n);
    out[OFF_W + k * DD + d] = __fdiv_rn(out[OFF_EMA + k * DD + d], cs);
}

extern "C" void kernel_launch(void* const* d_in, const int* in_sizes, int n_in,
                              void* d_out, int out_size, void* d_ws, size_t ws_size,
                              hipStream_t stream) {
    const float* z    = (const float*)d_in[0];
    const float* w    = (const float*)d_in[1];
    const float* ecs  = (const float*)d_in[2];
    const float* emaw = (const float*)d_in[3];
    float* out = (float*)d_out;

    // small scratch in ws (~164 KB, same footprint that already passed)
    int*   idx_ws  = (int*)d_ws;                       // NTOK ints
    float* x2v     = (float*)d_ws + NTOK;              // NTOK floats
    float* w2v     = x2v + NTOK;                       // KC floats
    float* lossacc = w2v + KC;                         // 1 float
    float* nsum    = lossacc + 1;                      // 1 float

    // big scratch inside not-yet-final d_out regions:
    float* wT   = out + OFF_W;                  // 256 x 8192 (8 MB), d-major
    float* vbuf = out + OFF_Q;                  // 16*NTOK floats (in Q region)
    int*   kbuf = (int*)(out + OFF_Q) + 16 * NTOK;

    k_prep   <<<11776, 256, 0, stream>>>(z, w, ecs, emaw, out, x2v, w2v, lossacc);
    k_argmin <<<1024,  256, 0, stream>>>(z, wT, x2v, w2v, vbuf, kbuf);
    k_reduce <<<NTOK / 256, 256, 0, stream>>>(vbuf, kbuf, idx_ws, out);
    k_scatter<<<NTOK,  256, 0, stream>>>(z, w, idx_ws, out, lossacc);
    k_nsum   <<<1,     256, 0, stream>>>(out, lossacc, nsum);
    k_neww   <<<KC,    256, 0, stream>>>(out, nsum);
}

// Round 6
// 1391.178 us; speedup vs baseline: 1.1694x; 1.1694x over previous
//
#include <hip/hip_runtime.h>

// VQ-VAE VectorQuantizer forward + EMA update, MI355X (gfx950).
// Distance argmin bit-exactly emulates the numpy fp32 reference:
//   dist = pairwise_sum(x*x) - 2*(sgemm single-FMA-chain) + pairwise_sum(w*w)
// R5 = R4 (128x128 tile, 8x8 acc, B register-prefetched from L2-resident wT)
// + fixed scratch lifetime: EMA region bytes aliased by vbuf/kbuf are
// re-initialized AFTER k_reduce (k_init2), not only in k_prep.

#define NTOK 16384
#define KC   8192
#define DD   256

#define OFF_Q    0
#define OFF_LOSS 4194304
#define OFF_IDX  4194305
#define OFF_W    4210689
#define OFF_CS   6307841
#define OFF_EMA  6316033

#define SCRN     262144     // floats of EMA region used as vbuf/kbuf scratch

#define DECAY_F  0.99f
#define OMD_F    0.01f
#define EPS_F    1e-5f
#define KEPS_F   0.08192f   // K * eps

typedef __attribute__((address_space(3))) unsigned int lds_u;
typedef const __attribute__((address_space(1))) unsigned int glob_u;

// ---- numpy-pairwise row squared-norm body (n=256): two 128 halves, 8
// strided accumulators each, butterfly combine — bit-exact vs numpy.
__device__ __forceinline__ void rownorm_body(const float* __restrict__ a,
                                             float* __restrict__ outn, int rb) {
    const int wave = threadIdx.x >> 6, lane = threadIdx.x & 63;
    const int row  = rb * 16 + wave * 4 + (lane >> 4);
    const int p    = lane & 15;
    const int h    = p >> 3, j = p & 7;
    const float* base = a + row * DD + h * 128 + j;
    float v = base[0];
    float r = __fmul_rn(v, v);
    #pragma unroll
    for (int t = 1; t < 16; ++t) {
        v = base[8 * t];
        r = __fadd_rn(r, __fmul_rn(v, v));
    }
    r = __fadd_rn(r, __shfl_xor(r, 1));
    r = __fadd_rn(r, __shfl_xor(r, 2));
    r = __fadd_rn(r, __shfl_xor(r, 4));
    r = __fadd_rn(r, __shfl_xor(r, 8));
    if (p == 0) outn[row] = r;
}

__device__ __forceinline__ void tr_body(const float* __restrict__ in,
                                        float* __restrict__ outT,
                                        int R, int C, int b) {
    __shared__ float s[32][33];
    const int tx = threadIdx.x & 31, ty = threadIdx.x >> 5;
    const int c0 = (b & 7) * 32, r0 = (b >> 3) * 32;
    #pragma unroll
    for (int i = 0; i < 4; ++i)
        s[ty + i * 8][tx] = in[(size_t)(r0 + ty + i * 8) * C + c0 + tx];
    __syncthreads();
    #pragma unroll
    for (int i = 0; i < 4; ++i)
        outT[(size_t)(c0 + ty + i * 8) * R + r0 + tx] = s[tx][ty + i * 8];
}

// -------- fused prep: z/w transposes + row norms + EMA init (one launch) ---
// NOTE: skips the first SCRN elements of the EMA region — those bytes carry
// vbuf/kbuf until k_reduce; k_init2 initializes them afterwards.
__global__ __launch_bounds__(256) void k_prep(const float* __restrict__ z,
                                              const float* __restrict__ w,
                                              const float* __restrict__ ecs,
                                              const float* __restrict__ emaw,
                                              float* __restrict__ out,
                                              float* __restrict__ x2v,
                                              float* __restrict__ w2v,
                                              float* __restrict__ lossacc) {
    const int b = blockIdx.x;
    if (b < 4096) {                               // z -> zT[256][16384]
        tr_body(z, out + OFF_Q, NTOK, DD, b);
    } else if (b < 6144) {                        // w -> wT[256][8192]
        tr_body(w, out + OFF_W, KC, DD, b - 4096);
    } else if (b < 7168) {
        rownorm_body(z, x2v, b - 6144);           // 1024 blocks: NTOK/16
    } else if (b < 7680) {
        rownorm_body(w, w2v, b - 7168);           // 512 blocks: KC/16
    } else {                                      // EMA init, 8192 blocks
        const int i = (b - 7680) * 256 + threadIdx.x;
        if (i >= SCRN) out[OFF_EMA + i] = __fmul_rn(DECAY_F, emaw[i]);
        if (i < KC) out[OFF_CS + i] = __fmul_rn(DECAY_F, ecs[i]);
        if (i == 0) *lossacc = 0.0f;
    }
}

// ---------------- argmin: A from LDS, B register-prefetched from wT --------
// grid 1024: split = blockIdx&7 (XCD-pinned 1MB wT slice), rb = blockIdx>>3.
// Each block: 128 rows x 1024 codes (8 tiles of 128), full D per tile.
// acc[i][j] = single fp32 FMA chain over d=0..255 ascending (BLAS-exact).
__global__ __launch_bounds__(256, 4) void k_argmin(
        const float* __restrict__ zT, const float* __restrict__ wT,
        const float* __restrict__ x2v, const float* __restrict__ w2v,
        float* __restrict__ vbuf, int* __restrict__ kbuf) {
    __shared__ float Zs[32][128];   // [d-in-chunk][row]  16 KB

    const int tid   = threadIdx.x;
    const int split = blockIdx.x & 7;
    const int rb    = blockIdx.x >> 3;
    const int n0    = rb * 128;
    const int cbase = split * 1024;
    const int tx4   = (tid & 15) * 4;
    const int ty4   = (tid >> 4) * 4;
    const int l     = tid & 63;
    const int wv    = tid >> 6;
    const int lcol  = (l & 31) * 4;
    const int lrow2 = l >> 5;

    float bestv[8];
    int   bestk[8];
    #pragma unroll
    for (int i = 0; i < 8; ++i) { bestv[i] = 1e30f; bestk[i] = 0; }

    for (int kt = 0; kt < 8; ++kt) {
        const int c0 = cbase + kt * 128;
        const float* __restrict__ wc0 = wT + c0 + tx4;        // + d*KC
        const float* __restrict__ wc1 = wT + c0 + 64 + tx4;
        float acc[8][8] = {};
        float4 b0 = *(const float4*)&wc0[0];                  // prefetch d=0
        float4 b1 = *(const float4*)&wc1[0];

        for (int dt = 0; dt < 8; ++dt) {
            const int d0 = dt * 32;
            __syncthreads();   // previous chunk's LDS reads done
            #pragma unroll
            for (int q = 0; q < 4; ++q) {
                const int m  = wv * 4 + q;        // 16 x 1KB segments
                const int dd = m * 2 + lrow2;     // 0..31
                __builtin_amdgcn_global_load_lds(
                    (glob_u*)(zT + (size_t)(d0 + dd) * NTOK + n0 + lcol),
                    (lds_u*)((char*)&Zs[0][0] + m * 1024 + l * 16), 16, 0, 0);
            }
            __syncthreads();
            #pragma unroll
            for (int dd = 0; dd < 32; ++dd) {
                const float4 cb0 = b0, cb1 = b1;
                const int dn = d0 + dd + 1 < DD ? d0 + dd + 1 : DD - 1;
                b0 = *(const float4*)&wc0[(size_t)dn * KC];   // prefetch d+1
                b1 = *(const float4*)&wc1[(size_t)dn * KC];
                const float4 a0 = *(const float4*)&Zs[dd][ty4];
                const float4 a1 = *(const float4*)&Zs[dd][64 + ty4];
                const float av[8] = {a0.x, a0.y, a0.z, a0.w,
                                     a1.x, a1.y, a1.z, a1.w};
                const float bw[8] = {cb0.x, cb0.y, cb0.z, cb0.w,
                                     cb1.x, cb1.y, cb1.z, cb1.w};
                #pragma unroll
                for (int i = 0; i < 8; ++i)
                    #pragma unroll
                    for (int j = 0; j < 8; ++j)
                        acc[i][j] = __fmaf_rn(av[i], bw[j], acc[i][j]);
            }
        }
        // dist = (x2 - 2*xe) + w2, per-op fp32 rounding; explicit (==, k<)
        // tie-break == np.argmin first-occurrence.
        #pragma unroll
        for (int j = 0; j < 8; ++j) {
            const int   code = c0 + ((j < 4) ? (tx4 + j) : (64 + tx4 + j - 4));
            const float w2   = w2v[code];
            #pragma unroll
            for (int i = 0; i < 8; ++i) {
                const int   row = n0 + ((i < 4) ? (ty4 + i) : (64 + ty4 + i - 4));
                const float x2  = x2v[row];
                const float dv  = __fadd_rn(
                    __fsub_rn(x2, __fmul_rn(2.0f, acc[i][j])), w2);
                if (dv < bestv[i] || (dv == bestv[i] && code < bestk[i])) {
                    bestv[i] = dv; bestk[i] = code;
                }
            }
        }
    }

    // reduce across tx (16 consecutive lanes share ty)
    #pragma unroll
    for (int i = 0; i < 8; ++i) {
        float bv = bestv[i];
        int   bk = bestk[i];
        #pragma unroll
        for (int off = 8; off; off >>= 1) {
            const float ov = __shfl_down(bv, off, 16);
            const int   ok = __shfl_down(bk, off, 16);
            if (ov < bv || (ov == bv && ok < bk)) { bv = ov; bk = ok; }
        }
        if ((tid & 15) == 0) {
            const int row = n0 + ((i < 4) ? (ty4 + i) : (64 + ty4 + i - 4));
            vbuf[split * NTOK + row] = bv;
            kbuf[split * NTOK + row] = bk;
        }
    }
}

// ---------------- combine the 8 split-candidates per row -------------------
__global__ __launch_bounds__(256) void k_reduce(const float* __restrict__ vbuf,
                                                const int* __restrict__ kbuf,
                                                int* __restrict__ idx_ws,
                                                float* __restrict__ out) {
    const int r = blockIdx.x * 256 + threadIdx.x;
    float bv = vbuf[r];
    int   bk = kbuf[r];
    #pragma unroll
    for (int s = 1; s < 8; ++s) {
        const float v = vbuf[s * NTOK + r];
        const int   k = kbuf[s * NTOK + r];
        if (v < bv || (v == bv && k < bk)) { bv = v; bk = k; }
    }
    idx_ws[r] = bk;
    out[OFF_IDX + r] = (float)bk;
}

// ------- init the EMA-region bytes that served as vbuf/kbuf scratch --------
__global__ __launch_bounds__(256) void k_init2(const float* __restrict__ emaw,
                                               float* __restrict__ out) {
    const int i = blockIdx.x * 256 + threadIdx.x;   // covers [0, SCRN)
    out[OFF_EMA + i] = __fmul_rn(DECAY_F, emaw[i]);
}

// ---------------- gather quantized + loss partial + EMA scatter ------------
__global__ __launch_bounds__(256) void k_scatter(const float* __restrict__ z,
                                                 const float* __restrict__ w,
                                                 const int* __restrict__ idx_ws,
                                                 float* __restrict__ out,
                                                 float* __restrict__ lossacc) {
    const int n = blockIdx.x, d = threadIdx.x;
    const int k = idx_ws[n];
    const float zv   = z[n * DD + d];
    const float q    = w[k * DD + d];
    const float diff = __fsub_rn(q, zv);
    out[OFF_Q + n * DD + d] = __fadd_rn(zv, diff);   // straight-through value

    float s = __fmul_rn(diff, diff);
    #pragma unroll
    for (int off = 32; off; off >>= 1) s += __shfl_down(s, off, 64);
    __shared__ float ps[4];
    if ((d & 63) == 0) ps[d >> 6] = s;
    __syncthreads();
    if (d == 0) atomicAdd(lossacc, ps[0] + ps[1] + ps[2] + ps[3]);

    atomicAdd(&out[OFF_EMA + k * DD + d], __fmul_rn(OMD_F, zv));
    if (d == 0) atomicAdd(&out[OFF_CS + k], OMD_F);
}

// ---------------- n = sum(new_cluster_size); finalize loss -----------------
__global__ __launch_bounds__(256) void k_nsum(float* __restrict__ out,
                                              const float* __restrict__ lossacc,
                                              float* __restrict__ nsum) {
    const int t = threadIdx.x;
    float s = 0.0f;
    for (int i = t; i < KC; i += 256) s += out[OFF_CS + i];
    #pragma unroll
    for (int off = 32; off; off >>= 1) s += __shfl_down(s, off, 64);
    __shared__ float ps[4];
    if ((t & 63) == 0) ps[t >> 6] = s;
    __syncthreads();
    if (t == 0) {
        *nsum = ps[0] + ps[1] + ps[2] + ps[3];
        out[OFF_LOSS] = 1.25f * (*lossacc) / 4194304.0f;
    }
}

// ---------------- new_weight = new_ema_w / laplace(cluster_size) -----------
__global__ __launch_bounds__(256) void k_neww(float* __restrict__ out,
                                              const float* __restrict__ nsum) {
    const int k = blockIdx.x, d = threadIdx.x;
    const float n  = *nsum;
    const float cs = __fmul_rn(__fdiv_rn(__fadd_rn(out[OFF_CS + k], EPS_F),
                                         __fadd_rn(n, KEPS_F)), n);
    out[OFF_W + k * DD + d] = __fdiv_rn(out[OFF_EMA + k * DD + d], cs);
}

extern "C" void kernel_launch(void* const* d_in, const int* in_sizes, int n_in,
                              void* d_out, int out_size, void* d_ws, size_t ws_size,
                              hipStream_t stream) {
    const float* z    = (const float*)d_in[0];
    const float* w    = (const float*)d_in[1];
    const float* ecs  = (const float*)d_in[2];
    const float* emaw = (const float*)d_in[3];
    float* out = (float*)d_out;

    // small scratch in ws (~164 KB, same footprint that already passed)
    int*   idx_ws  = (int*)d_ws;                       // NTOK ints
    float* x2v     = (float*)d_ws + NTOK;              // NTOK floats
    float* w2v     = x2v + NTOK;                       // KC floats
    float* lossacc = w2v + KC;                         // 1 float
    float* nsum    = lossacc + 1;                      // 1 float

    // big scratch inside not-yet-final d_out regions:
    float* zT   = out + OFF_Q;                  // 256 x 16384 (16 MB), d-major
    float* wT   = out + OFF_W;                  // 256 x 8192  ( 8 MB), d-major
    float* vbuf = out + OFF_EMA;                // 8*NTOK floats (EMA region,
    int*   kbuf = (int*)(out + OFF_EMA) + 8 * NTOK;  // re-inited by k_init2)

    k_prep   <<<15872, 256, 0, stream>>>(z, w, ecs, emaw, out, x2v, w2v, lossacc);
    k_argmin <<<1024,  256, 0, stream>>>(zT, wT, x2v, w2v, vbuf, kbuf);
    k_reduce <<<NTOK / 256, 256, 0, stream>>>(vbuf, kbuf, idx_ws, out);
    k_init2  <<<SCRN / 256, 256, 0, stream>>>(emaw, out);
    k_scatter<<<NTOK,  256, 0, stream>>>(z, w, idx_ws, out, lossacc);
    k_nsum   <<<1,     256, 0, stream>>>(out, lossacc, nsum);
    k_neww   <<<KC,    256, 0, stream>>>(out, nsum);
}